// Round 1
// baseline (727.200 us; speedup 1.0000x reference)
//
#include <hip/hip_runtime.h>
#include <hip/hip_bf16.h>
#include <math.h>

// Problem constants
#define BATCH 16
#define CIN   128
#define COUT  256
#define KS    3
#define HH    56
#define WW    56
#define NTAP  9                 // K*K
#define NE    (COUT*CIN*NTAP)   // 294912 weight elements
#define HW    (HH*WW)           // 3136

// Workspace layout (in floats)
#define WS_CTX   0                       // [16][128]
#define WS_ASP   2048                    // [16][16] (9 used)
#define WS_AIN   2304                    // [16][128]
#define WS_AOUT  4352                    // [16][256]
#define WS_DYN   8448                    // [16][NE]  layout dyn[b][(ic*9+tap)*256 + oc]

// ---------------------------------------------------------------------------
// K1: context[b,c] = mean over H,W of x[b,c,:,:]
__global__ void k_context(const float* __restrict__ x, float* __restrict__ ctx) {
    int bc = blockIdx.x;                       // 0..2047
    const float* p = x + (size_t)bc * HW;
    float s = 0.f;
    for (int i = threadIdx.x; i < HW; i += 256) s += p[i];
    // wave reduce (64 lanes)
    for (int off = 32; off > 0; off >>= 1) s += __shfl_down(s, off, 64);
    __shared__ float red[4];
    if ((threadIdx.x & 63) == 0) red[threadIdx.x >> 6] = s;
    __syncthreads();
    if (threadIdx.x == 0) {
        float t = red[0] + red[1] + red[2] + red[3];
        ctx[bc] = t * (1.f / (float)HW);
    }
}

// ---------------------------------------------------------------------------
// K2: small attention vectors (spatial 9, in 128, out 256) per batch
__global__ void k_attn(const float* __restrict__ ctx,
                       const float* __restrict__ wsp, const float* __restrict__ bsp,
                       const float* __restrict__ win, const float* __restrict__ bin,
                       const float* __restrict__ wout, const float* __restrict__ bout,
                       float* __restrict__ ws) {
    int b = blockIdx.x;
    __shared__ float c[CIN];
    if (threadIdx.x < CIN) c[threadIdx.x] = ctx[b * CIN + threadIdx.x];
    __syncthreads();
    float* a_sp  = ws + WS_ASP  + b * 16;
    float* a_in  = ws + WS_AIN  + b * CIN;
    float* a_out = ws + WS_AOUT + b * COUT;
    for (int idx = threadIdx.x; idx < 9 + CIN + COUT; idx += 256) {
        const float* w; float bias; float* o; int r;
        if (idx < 9)            { r = idx;           w = wsp  + r * CIN; bias = bsp[r];  o = a_sp;  }
        else if (idx < 9 + CIN) { r = idx - 9;       w = win  + r * CIN; bias = bin[r];  o = a_in;  }
        else                    { r = idx - 9 - CIN; w = wout + r * CIN; bias = bout[r]; o = a_out; }
        float s = bias;
        for (int j = 0; j < CIN; ++j) s = fmaf(c[j], w[j], s);
        o[r] = 1.f / (1.f + __expf(-s));
    }
}

// ---------------------------------------------------------------------------
// K3: fused attn_kernel GEMV (all 16 batches per weight row) + dyn build.
// Thread m indexes output layout (ic*9+tap)*256 + oc; weight row e=((oc*128+ic)*9+tap).
__global__ void k_build(const float* __restrict__ ctx,
                        const float* __restrict__ wk, const float* __restrict__ bk,
                        const float* __restrict__ base, float* __restrict__ ws) {
    int m = blockIdx.x * 256 + threadIdx.x;    // 0..NE-1
    int oc  = m & 255;
    int kt  = m >> 8;          // ic*9+tap
    int tap = kt % 9;
    int ic  = kt / 9;
    int e   = (oc * CIN + ic) * NTAP + tap;

    __shared__ float4 c4[BATCH * (CIN / 4)];   // ctx for all 16 batches
    for (int i = threadIdx.x; i < BATCH * (CIN / 4); i += 256)
        c4[i] = ((const float4*)ctx)[i];
    __syncthreads();

    float bias = bk[e];
    float acc[BATCH];
#pragma unroll
    for (int b = 0; b < BATCH; ++b) acc[b] = bias;

    const float4* w4 = (const float4*)(wk + (size_t)e * CIN);
    for (int j = 0; j < CIN / 4; ++j) {
        float4 wv = w4[j];
#pragma unroll
        for (int b = 0; b < BATCH; ++b) {
            float4 cv = c4[b * (CIN / 4) + j];
            acc[b] = fmaf(wv.x, cv.x, fmaf(wv.y, cv.y, fmaf(wv.z, cv.z, fmaf(wv.w, cv.w, acc[b]))));
        }
    }

    float bsc = base[e];
    const float* a_sp  = ws + WS_ASP;
    const float* a_in  = ws + WS_AIN;
    const float* a_out = ws + WS_AOUT;
    float* dyn = ws + WS_DYN;
#pragma unroll
    for (int b = 0; b < BATCH; ++b) {
        float s = 1.f / (1.f + __expf(-acc[b]));
        float v = bsc * s * a_out[b * COUT + oc] * a_in[b * CIN + ic] * a_sp[b * 16 + tap];
        dyn[(size_t)b * NE + m] = v;
    }
}

// ---------------------------------------------------------------------------
// K4: per-sample 3x3 conv, fp32 direct with LDS tiles.
// Block: b = blockIdx.z, oc tile 64 (blockIdx.y), 4 output rows (blockIdx.x).
// Thread: 8 oc x 7 cols register tile.
#define OCT 64
#define RT  4
#define ICB 8
__global__ __launch_bounds__(256) void k_conv(const float* __restrict__ x,
                                              const float* __restrict__ ws,
                                              const float* __restrict__ bias,
                                              float* __restrict__ out) {
    const int b   = blockIdx.z;
    const int oc0 = blockIdx.y * OCT;
    const int r0  = blockIdx.x * RT;

    const int ocg  = threadIdx.x >> 5;        // 0..7
    const int oc_t = ocg * 8;                 // thread's oc offset in tile
    const int pxg  = threadIdx.x & 31;
    const int prow = pxg >> 3;                // 0..3
    const int col0 = (pxg & 7) * 7;           // 0,7,...,49

    __shared__ float sx[ICB * 6 * 58];        // x tile with halo, zero padded
    __shared__ float sw[ICB * NTAP * OCT];    // dyn tile [ic][tap][oc]

    const float* dyn_b = ws + WS_DYN + (size_t)b * NE;
    const float* x_b   = x + (size_t)b * CIN * HW;

    float acc[8][7];
#pragma unroll
    for (int i = 0; i < 8; ++i)
#pragma unroll
        for (int j = 0; j < 7; ++j) acc[i][j] = 0.f;

    for (int icc = 0; icc < CIN / ICB; ++icc) {
        __syncthreads();
        // stage x tile: ic chunk x rows [r0-1, r0+4] x cols [-1,56]
        for (int idx = threadIdx.x; idx < ICB * 6 * 58; idx += 256) {
            int ic_l = idx / (6 * 58);
            int rem  = idx % (6 * 58);
            int ry   = rem / 58;
            int cx   = rem % 58;
            int gy   = r0 + ry - 1;
            int gx   = cx - 1;
            float v = 0.f;
            if (gy >= 0 && gy < HH && gx >= 0 && gx < WW)
                v = x_b[(size_t)(icc * ICB + ic_l) * HW + gy * WW + gx];
            sx[idx] = v;
        }
        // stage dyn tile: [ic][tap][oc] contiguous in global (coalesced)
        for (int idx = threadIdx.x; idx < ICB * NTAP * OCT; idx += 256) {
            int kt   = idx >> 6;               // ic_l*9+tap
            int oc_l = idx & 63;
            sw[idx] = dyn_b[(size_t)(icc * (ICB * NTAP) + kt) * COUT + oc0 + oc_l];
        }
        __syncthreads();

        for (int ic_l = 0; ic_l < ICB; ++ic_l) {
#pragma unroll
            for (int dy = 0; dy < 3; ++dy) {
#pragma unroll
                for (int dx = 0; dx < 3; ++dx) {
                    const float* swp = &sw[((ic_l * NTAP + dy * 3 + dx) << 6) + oc_t];
                    float a[8];
#pragma unroll
                    for (int i = 0; i < 8; ++i) a[i] = swp[i];
                    const float* sxp = &sx[(ic_l * 6 + prow + dy) * 58 + col0 + dx];
                    float bv[7];
#pragma unroll
                    for (int j = 0; j < 7; ++j) bv[j] = sxp[j];
#pragma unroll
                    for (int i = 0; i < 8; ++i)
#pragma unroll
                        for (int j = 0; j < 7; ++j)
                            acc[i][j] = fmaf(a[i], bv[j], acc[i][j]);
                }
            }
        }
    }

    // epilogue
#pragma unroll
    for (int i = 0; i < 8; ++i) {
        int oc = oc0 + oc_t + i;
        float bs = bias[oc];
        float* op = out + ((size_t)(b * COUT + oc) * HH + (r0 + prow)) * WW + col0;
#pragma unroll
        for (int j = 0; j < 7; ++j) op[j] = acc[i][j] + bs;
    }
}

// ---------------------------------------------------------------------------
extern "C" void kernel_launch(void* const* d_in, const int* in_sizes, int n_in,
                              void* d_out, int out_size, void* d_ws, size_t ws_size,
                              hipStream_t stream) {
    const float* x    = (const float*)d_in[0];
    const float* base = (const float*)d_in[1];
    const float* bias = (const float*)d_in[2];
    const float* wsp  = (const float*)d_in[3];
    const float* bsp  = (const float*)d_in[4];
    const float* win  = (const float*)d_in[5];
    const float* bin  = (const float*)d_in[6];
    const float* wout = (const float*)d_in[7];
    const float* bout = (const float*)d_in[8];
    const float* wk   = (const float*)d_in[9];
    const float* bk   = (const float*)d_in[10];
    float* out = (float*)d_out;
    float* ws  = (float*)d_ws;

    k_context<<<BATCH * CIN, 256, 0, stream>>>(x, ws + WS_CTX);
    k_attn<<<BATCH, 256, 0, stream>>>(ws + WS_CTX, wsp, bsp, win, bin, wout, bout, ws);
    k_build<<<NE / 256, 256, 0, stream>>>(ws + WS_CTX, wk, bk, base, ws);
    dim3 cgrid(HH / RT, COUT / OCT, BATCH);
    k_conv<<<cgrid, 256, 0, stream>>>(x, ws, bias, out);
}

// Round 2
// 345.946 us; speedup vs baseline: 2.1021x; 2.1021x over previous
//
#include <hip/hip_runtime.h>
#include <hip/hip_bf16.h>
#include <math.h>

#define BATCH 16
#define CIN   128
#define COUT  256
#define HH    56
#define WW    56
#define HW    3136
#define NTAP  9
#define NE    (COUT*CIN*NTAP)   // 294912

typedef short short8 __attribute__((ext_vector_type(8)));
typedef float floatx4 __attribute__((ext_vector_type(4)));

// workspace layout (byte offsets, all 256-aligned)
#define WSB_CTX   0                          // fp32 [16][128]
#define WSB_ASP   8192                       // fp32 [16][16] (9 used)
#define WSB_AIN   9472                       // fp32 [16][128]
#define WSB_AOUT  17664                      // fp32 [16][256]
#define WSB_XT    34048                      // bf16 [16][3136][128]
#define WSB_DYN   (WSB_XT + BATCH*HW*CIN*2)  // bf16 [16][9][256][128]  (tap,oc,ic)

// fp32 -> bf16 RNE
static __device__ inline unsigned short f2b(float f) {
    union { float f; unsigned u; } v; v.f = f;
    unsigned r = v.u + 0x7FFF + ((v.u >> 16) & 1);
    return (unsigned short)(r >> 16);
}
static __device__ inline short8 pack8(float4 a, float4 b) {
    short8 r;
    r[0] = (short)f2b(a.x); r[1] = (short)f2b(a.y); r[2] = (short)f2b(a.z); r[3] = (short)f2b(a.w);
    r[4] = (short)f2b(b.x); r[5] = (short)f2b(b.y); r[6] = (short)f2b(b.z); r[7] = (short)f2b(b.w);
    return r;
}

// ---------------------------------------------------------------------------
// K1: context[b,c] = mean(x[b,c,:,:])
__global__ void k_context(const float* __restrict__ x, float* __restrict__ ctx) {
    int bc = blockIdx.x;
    const float4* p = (const float4*)(x + (size_t)bc * HW);
    float s = 0.f;
    for (int i = threadIdx.x; i < HW / 4; i += 256) { float4 v = p[i]; s += v.x + v.y + v.z + v.w; }
    for (int off = 32; off; off >>= 1) s += __shfl_down(s, off, 64);
    __shared__ float red[4];
    if ((threadIdx.x & 63) == 0) red[threadIdx.x >> 6] = s;
    __syncthreads();
    if (threadIdx.x == 0) ctx[bc] = (red[0] + red[1] + red[2] + red[3]) * (1.f / (float)HW);
}

// ---------------------------------------------------------------------------
// K2: x transpose+cast: xt[b][pix][ic] bf16. Thread: 1 pixel x 32 ic.
__global__ void k_xt(const float* __restrict__ x, unsigned short* __restrict__ xt) {
    int b = blockIdx.y;
    int p = blockIdx.x * 64 + (threadIdx.x & 63);
    int icq = threadIdx.x >> 6;               // 0..3 -> ic base icq*32
    const float* xb = x + (size_t)b * CIN * HW + p;
    unsigned short tmp[32];
#pragma unroll
    for (int j = 0; j < 32; ++j) tmp[j] = f2b(xb[(size_t)(icq * 32 + j) * HW]);
    uint4* dst = (uint4*)(xt + ((size_t)b * HW + p) * CIN + icq * 32);
    const uint4* s = (const uint4*)tmp;
    dst[0] = s[0]; dst[1] = s[1]; dst[2] = s[2]; dst[3] = s[3];
}

// ---------------------------------------------------------------------------
// K3: small gates — one wave per GEMV row (spatial 9 / in 128 / out 256 per b)
__global__ void k_attn(const float* __restrict__ ctx,
                       const float* __restrict__ wsp, const float* __restrict__ bsp,
                       const float* __restrict__ win, const float* __restrict__ bin,
                       const float* __restrict__ wout, const float* __restrict__ bout,
                       float* __restrict__ asp, float* __restrict__ ain, float* __restrict__ aout) {
    int R = blockIdx.x * 4 + (threadIdx.x >> 6);   // 0..6287
    int lane = threadIdx.x & 63;
    int b = R / 393, r = R % 393;
    const float* w; float bias; float* o;
    if (r < 9)        { w = wsp  + r * CIN;         bias = bsp[r];         o = asp  + b * 16  + r; }
    else if (r < 137) { w = win  + (r - 9) * CIN;   bias = bin[r - 9];     o = ain  + b * CIN + (r - 9); }
    else              { w = wout + (r - 137) * CIN; bias = bout[r - 137];  o = aout + b * COUT + (r - 137); }
    float2 wv = ((const float2*)w)[lane];
    float2 cv = ((const float2*)(ctx + b * CIN))[lane];
    float d = wv.x * cv.x + wv.y * cv.y;
    for (int off = 32; off; off >>= 1) d += __shfl_down(d, off, 64);
    if (lane == 0) *o = 1.f / (1.f + __expf(-(d + bias)));
}

// ---------------------------------------------------------------------------
// K4: dyn build as skinny MFMA GEMM: logits[16, NE] = ctx @ wk^T, then gates.
// n enumerates (tap, oc, ic); e(n) = (oc*128+ic)*9 + tap. Output dyn[b][n] bf16.
__global__ void k_build(const float* __restrict__ ctx, const float* __restrict__ wk,
                        const float* __restrict__ bk, const float* __restrict__ base,
                        const float* __restrict__ asp, const float* __restrict__ ain,
                        const float* __restrict__ aout, unsigned short* __restrict__ dyn) {
    int wid = threadIdx.x >> 6, l = threadIdx.x & 63;
    int lq = l & 15, quad = l >> 4;
    // A frags: ctx[b=lq][k = kc*32 + quad*8 + j]
    short8 afr[4];
    const float* arow = ctx + lq * CIN;
#pragma unroll
    for (int kc = 0; kc < 4; ++kc) {
        float4 v0 = *(const float4*)(arow + kc * 32 + quad * 8);
        float4 v1 = *(const float4*)(arow + kc * 32 + quad * 8 + 4);
        afr[kc] = pack8(v0, v1);
    }
    int n0w = blockIdx.x * 512 + wid * 128;
    for (int nf = 0; nf < 8; ++nf) {
        int n0 = n0w + nf * 16;
        int ic  = (n0 & 127) + lq;
        int oc  = (n0 >> 7) & 255;
        int tap = n0 >> 15;
        int e = (oc * CIN + ic) * NTAP + tap;
        const float* wrow = wk + (size_t)e * CIN;
        floatx4 acc = {0.f, 0.f, 0.f, 0.f};
#pragma unroll
        for (int kc = 0; kc < 4; ++kc) {
            float4 v0 = *(const float4*)(wrow + kc * 32 + quad * 8);
            float4 v1 = *(const float4*)(wrow + kc * 32 + quad * 8 + 4);
            short8 bfr = pack8(v0, v1);
            acc = __builtin_amdgcn_mfma_f32_16x16x32_bf16(afr[kc], bfr, acc, 0, 0, 0);
        }
        float bke = bk[e], bse = base[e];
#pragma unroll
        for (int r = 0; r < 4; ++r) {
            int b = quad * 4 + r;
            float s = 1.f / (1.f + __expf(-(acc[r] + bke)));
            float v = bse * s * aout[b * COUT + oc] * ain[b * CIN + ic] * asp[b * 16 + tap];
            dyn[(size_t)b * NE + n0 + lq] = f2b(v);
        }
    }
}

// ---------------------------------------------------------------------------
// K5: conv as MFMA implicit GEMM. Block: b, 128 oc, 4 rows (N=224 pixels).
// 4 waves in 2x2; wave tile M=64 x N=112 (4 m-frags x 7 n-frags, 16x16x32 bf16).
// K-loop: 4 ic-chunks of 32; per chunk, 9 taps with double-buffered A tiles.
__global__ __launch_bounds__(256, 2) void k_conv(
    const unsigned short* __restrict__ xt, const unsigned short* __restrict__ dyn,
    const float* __restrict__ bias, float* __restrict__ out) {
    __shared__ char s_x[348 * 80];      // [6 rows x 58 cols][32 ic bf16 + 16B pad]
    __shared__ char s_a[2][128 * 80];   // [128 oc][32 ic bf16 + 16B pad], double-buffered
    int b = blockIdx.z, oc0 = blockIdx.y * 128, r0 = blockIdx.x * 4;
    int tid = threadIdx.x;
    int wid = tid >> 6, l = tid & 63, lq = l & 15, quad = l >> 4;
    int wm = wid & 1, wn = wid >> 1;
    const unsigned short* xtb  = xt  + (size_t)b * HW * CIN;
    const unsigned short* dynb = dyn + (size_t)b * NE;

    int pixaddr[7];
#pragma unroll
    for (int nf = 0; nf < 7; ++nf) {
        int n = wn * 112 + nf * 16 + lq;
        int ry = n / 56, cx = n % 56;
        pixaddr[nf] = (ry * 58 + cx) * 80 + quad * 16;
    }

    floatx4 acc[4][7];
#pragma unroll
    for (int i = 0; i < 4; ++i)
#pragma unroll
        for (int j = 0; j < 7; ++j) acc[i][j] = (floatx4){0.f, 0.f, 0.f, 0.f};

    for (int kc = 0; kc < 4; ++kc) {
        // stage x tile (rows r0-1..r0+4, cols -1..56, zero-padded), [pix][32ic]
        for (int u = tid; u < 1392; u += 256) {
            int icq = u & 3, pix = u >> 2;
            int ry = pix / 58, cx = pix % 58;
            int gy = r0 + ry - 1, gx = cx - 1;
            uint4 v = {0u, 0u, 0u, 0u};
            if (gy >= 0 && gy < HH && gx >= 0 && gx < WW)
                v = *(const uint4*)(xtb + (size_t)(gy * WW + gx) * CIN + kc * 32 + icq * 8);
            *(uint4*)(s_x + pix * 80 + icq * 16) = v;
        }
        // stage A for tap 0 into buf 0
        for (int u = tid; u < 512; u += 256) {
            int icq = u & 3, oc = u >> 2;
            *(uint4*)(s_a[0] + oc * 80 + icq * 16) =
                *(const uint4*)(dynb + (size_t)(oc0 + oc) * CIN + kc * 32 + icq * 8);
        }
        __syncthreads();
#pragma unroll
        for (int tap = 0; tap < 9; ++tap) {
            if (tap < 8) {  // prefetch next tap's A into the other buffer
                for (int u = tid; u < 512; u += 256) {
                    int icq = u & 3, oc = u >> 2;
                    *(uint4*)(s_a[(tap + 1) & 1] + oc * 80 + icq * 16) =
                        *(const uint4*)(dynb + (size_t)((tap + 1) * COUT + oc0 + oc) * CIN + kc * 32 + icq * 8);
                }
            }
            const char* sa = s_a[tap & 1];
            short8 af[4];
#pragma unroll
            for (int mf = 0; mf < 4; ++mf)
                af[mf] = *(const short8*)(sa + (wm * 64 + mf * 16 + lq) * 80 + quad * 16);
            int toff = ((tap / 3) * 58 + (tap % 3)) * 80;
#pragma unroll
            for (int nf = 0; nf < 7; ++nf) {
                short8 bf = *(const short8*)(s_x + pixaddr[nf] + toff);
#pragma unroll
                for (int mf = 0; mf < 4; ++mf)
                    acc[mf][nf] = __builtin_amdgcn_mfma_f32_16x16x32_bf16(af[mf], bf, acc[mf][nf], 0, 0, 0);
            }
            __syncthreads();
        }
    }

    // epilogue: D[m=quad*4+r][n=lq] per frag; add bias, store fp32
#pragma unroll
    for (int mf = 0; mf < 4; ++mf) {
#pragma unroll
        for (int r = 0; r < 4; ++r) {
            int oc = oc0 + wm * 64 + mf * 16 + quad * 4 + r;
            float bs = bias[oc];
            float* ob = out + (size_t)(b * COUT + oc) * HW + r0 * WW + wn * 112 + lq;
#pragma unroll
            for (int nf = 0; nf < 7; ++nf)
                ob[nf * 16] = acc[mf][nf][r] + bs;
        }
    }
}

// ---------------------------------------------------------------------------
extern "C" void kernel_launch(void* const* d_in, const int* in_sizes, int n_in,
                              void* d_out, int out_size, void* d_ws, size_t ws_size,
                              hipStream_t stream) {
    const float* x    = (const float*)d_in[0];
    const float* base = (const float*)d_in[1];
    const float* bias = (const float*)d_in[2];
    const float* wsp  = (const float*)d_in[3];
    const float* bsp  = (const float*)d_in[4];
    const float* win  = (const float*)d_in[5];
    const float* bin  = (const float*)d_in[6];
    const float* wout = (const float*)d_in[7];
    const float* bout = (const float*)d_in[8];
    const float* wk   = (const float*)d_in[9];
    const float* bk   = (const float*)d_in[10];
    float* out = (float*)d_out;
    char* ws = (char*)d_ws;

    float* ctx  = (float*)(ws + WSB_CTX);
    float* asp  = (float*)(ws + WSB_ASP);
    float* ain  = (float*)(ws + WSB_AIN);
    float* aout = (float*)(ws + WSB_AOUT);
    unsigned short* xt  = (unsigned short*)(ws + WSB_XT);
    unsigned short* dyn = (unsigned short*)(ws + WSB_DYN);

    k_context<<<BATCH * CIN, 256, 0, stream>>>(x, ctx);
    k_xt<<<dim3(HW / 64, BATCH), 256, 0, stream>>>(x, xt);
    k_attn<<<(BATCH * 393) / 4, 256, 0, stream>>>(ctx, wsp, bsp, win, bin, wout, bout, asp, ain, aout);
    k_build<<<NE / 512, 256, 0, stream>>>(ctx, wk, bk, base, asp, ain, aout, dyn);
    k_conv<<<dim3(HH / 4, COUT / 128, BATCH), 256, 0, stream>>>(xt, dyn, bias, out);
}

// Round 3
// 332.498 us; speedup vs baseline: 2.1871x; 1.0404x over previous
//
#include <hip/hip_runtime.h>
#include <hip/hip_bf16.h>
#include <math.h>

#define BATCH 16
#define CIN   128
#define COUT  256
#define HH    56
#define WW    56
#define HW    3136
#define NTAP  9
#define NE    (COUT*CIN*NTAP)   // 294912

typedef short short8 __attribute__((ext_vector_type(8)));
typedef float floatx4 __attribute__((ext_vector_type(4)));

// workspace layout (byte offsets, all 256-aligned)
#define WSB_CTX   0                          // fp32 [16][128]
#define WSB_ASP   8192                       // fp32 [16][16] (9 used)
#define WSB_AIN   9472                       // fp32 [16][128]
#define WSB_AOUT  17664                      // fp32 [16][256]
#define WSB_XT    34048                      // bf16 [16][3136][128]
#define WSB_DYN   (WSB_XT + BATCH*HW*CIN*2)  // bf16 [16][9][256][128]  (tap,oc,ic)

// fp32 -> bf16 RNE
static __device__ inline unsigned short f2b(float f) {
    union { float f; unsigned u; } v; v.f = f;
    unsigned r = v.u + 0x7FFF + ((v.u >> 16) & 1);
    return (unsigned short)(r >> 16);
}
static __device__ inline short8 pack8(float4 a, float4 b) {
    short8 r;
    r[0] = (short)f2b(a.x); r[1] = (short)f2b(a.y); r[2] = (short)f2b(a.z); r[3] = (short)f2b(a.w);
    r[4] = (short)f2b(b.x); r[5] = (short)f2b(b.y); r[6] = (short)f2b(b.z); r[7] = (short)f2b(b.w);
    return r;
}

// ---------------------------------------------------------------------------
// K1: context[b,c] = mean(x[b,c,:,:])
__global__ void k_context(const float* __restrict__ x, float* __restrict__ ctx) {
    int bc = blockIdx.x;
    const float4* p = (const float4*)(x + (size_t)bc * HW);
    float s = 0.f;
    for (int i = threadIdx.x; i < HW / 4; i += 256) { float4 v = p[i]; s += v.x + v.y + v.z + v.w; }
    for (int off = 32; off; off >>= 1) s += __shfl_down(s, off, 64);
    __shared__ float red[4];
    if ((threadIdx.x & 63) == 0) red[threadIdx.x >> 6] = s;
    __syncthreads();
    if (threadIdx.x == 0) ctx[bc] = (red[0] + red[1] + red[2] + red[3]) * (1.f / (float)HW);
}

// ---------------------------------------------------------------------------
// K2: x transpose+cast: xt[b][pix][ic] bf16. Thread: 1 pixel x 32 ic.
__global__ void k_xt(const float* __restrict__ x, unsigned short* __restrict__ xt) {
    int b = blockIdx.y;
    int p = blockIdx.x * 64 + (threadIdx.x & 63);
    int icq = threadIdx.x >> 6;               // 0..3 -> ic base icq*32
    const float* xb = x + (size_t)b * CIN * HW + p;
    unsigned short tmp[32];
#pragma unroll
    for (int j = 0; j < 32; ++j) tmp[j] = f2b(xb[(size_t)(icq * 32 + j) * HW]);
    uint4* dst = (uint4*)(xt + ((size_t)b * HW + p) * CIN + icq * 32);
    const uint4* s = (const uint4*)tmp;
    dst[0] = s[0]; dst[1] = s[1]; dst[2] = s[2]; dst[3] = s[3];
}

// ---------------------------------------------------------------------------
// K3: small gates — one wave per GEMV row
__global__ void k_attn(const float* __restrict__ ctx,
                       const float* __restrict__ wsp, const float* __restrict__ bsp,
                       const float* __restrict__ win, const float* __restrict__ bin,
                       const float* __restrict__ wout, const float* __restrict__ bout,
                       float* __restrict__ asp, float* __restrict__ ain, float* __restrict__ aout) {
    int R = blockIdx.x * 4 + (threadIdx.x >> 6);
    int lane = threadIdx.x & 63;
    int b = R / 393, r = R % 393;
    const float* w; float bias; float* o;
    if (r < 9)        { w = wsp  + r * CIN;         bias = bsp[r];         o = asp  + b * 16  + r; }
    else if (r < 137) { w = win  + (r - 9) * CIN;   bias = bin[r - 9];     o = ain  + b * CIN + (r - 9); }
    else              { w = wout + (r - 137) * CIN; bias = bout[r - 137];  o = aout + b * COUT + (r - 137); }
    float2 wv = ((const float2*)w)[lane];
    float2 cv = ((const float2*)(ctx + b * CIN))[lane];
    float d = wv.x * cv.x + wv.y * cv.y;
    for (int off = 32; off; off >>= 1) d += __shfl_down(d, off, 64);
    if (lane == 0) *o = 1.f / (1.f + __expf(-(d + bias)));
}

// ---------------------------------------------------------------------------
// K4: dyn build, skinny MFMA GEMM; each wave handles 64 n (4 frags of 16).
// n enumerates (tap, oc, ic); e(n) = (oc*128+ic)*9 + tap. dyn[b][n] bf16.
__global__ void k_build(const float* __restrict__ ctx, const float* __restrict__ wk,
                        const float* __restrict__ bk, const float* __restrict__ base,
                        const float* __restrict__ asp, const float* __restrict__ ain,
                        const float* __restrict__ aout, unsigned short* __restrict__ dyn) {
    int wid = threadIdx.x >> 6, l = threadIdx.x & 63;
    int lq = l & 15, quad = l >> 4;
    short8 afr[4];
    const float* arow = ctx + lq * CIN;
#pragma unroll
    for (int kc = 0; kc < 4; ++kc) {
        float4 v0 = *(const float4*)(arow + kc * 32 + quad * 8);
        float4 v1 = *(const float4*)(arow + kc * 32 + quad * 8 + 4);
        afr[kc] = pack8(v0, v1);
    }
    int n0w = blockIdx.x * 256 + wid * 64;
    for (int nf = 0; nf < 4; ++nf) {
        int n0 = n0w + nf * 16;
        int ic  = (n0 & 127) + lq;
        int oc  = (n0 >> 7) & 255;
        int tap = n0 >> 15;
        int e = (oc * CIN + ic) * NTAP + tap;
        const float* wrow = wk + (size_t)e * CIN;
        floatx4 acc = {0.f, 0.f, 0.f, 0.f};
#pragma unroll
        for (int kc = 0; kc < 4; ++kc) {
            float4 v0 = *(const float4*)(wrow + kc * 32 + quad * 8);
            float4 v1 = *(const float4*)(wrow + kc * 32 + quad * 8 + 4);
            short8 bfr = pack8(v0, v1);
            acc = __builtin_amdgcn_mfma_f32_16x16x32_bf16(afr[kc], bfr, acc, 0, 0, 0);
        }
        float bke = bk[e], bse = base[e];
#pragma unroll
        for (int r = 0; r < 4; ++r) {
            int b = quad * 4 + r;
            float s = 1.f / (1.f + __expf(-(acc[r] + bke)));
            float v = bse * s * aout[b * COUT + oc] * ain[b * CIN + ic] * asp[b * 16 + tap];
            dyn[(size_t)b * NE + n0 + lq] = f2b(v);
        }
    }
}

// ---------------------------------------------------------------------------
// K5: conv as MFMA implicit GEMM. Block: b, 64 oc, 8 output rows.
// A-tile (all 9 taps x 64 oc x 32 ic) + x-tile (10 rows x 58 cols x 32 ic)
// resident in LDS; only 2 barriers per ic-chunk. 4 waves, each wave:
// all 64 oc (4 m-frags) x 112 pixels = 2 rows (7 n-frags).
__global__ __launch_bounds__(256, 2) void k_conv(
    const unsigned short* __restrict__ xt, const unsigned short* __restrict__ dyn,
    const float* __restrict__ bias, float* __restrict__ out) {
    __shared__ char s_x[580 * 64];   // [tr*58+col][32 ic], 64-B rows (balanced for b128)
    __shared__ char s_a[576 * 64];   // [tap*64+oc][32 ic]
    int b = blockIdx.z, oc0 = blockIdx.y * 64, r0 = blockIdx.x * 8;
    int tid = threadIdx.x;
    int wn = tid >> 6, l = tid & 63, lq = l & 15, quad = l >> 4;
    const unsigned short* xtb  = xt  + (size_t)b * HW * CIN;
    const unsigned short* dynb = dyn + (size_t)b * NE;

    int pixaddr[7];
#pragma unroll
    for (int nf = 0; nf < 7; ++nf) {
        int n = nf * 16 + lq;                       // 0..111 within wave's 2 rows
        int tr = wn * 2 + n / 56, col = n % 56;
        pixaddr[nf] = (tr * 58 + col) * 64 + quad * 16;
    }

    floatx4 acc[4][7];
#pragma unroll
    for (int i = 0; i < 4; ++i)
#pragma unroll
        for (int j = 0; j < 7; ++j) acc[i][j] = (floatx4){0.f, 0.f, 0.f, 0.f};

    for (int kc = 0; kc < 4; ++kc) {
        __syncthreads();
        // stage x tile: rows r0-1..r0+8, cols -1..56, zero-padded
        for (int u = tid; u < 2320; u += 256) {
            int icq = u & 3, pix = u >> 2;
            int ry = pix / 58, cx = pix % 58;
            int gy = r0 + ry - 1, gx = cx - 1;
            uint4 v = {0u, 0u, 0u, 0u};
            if (gy >= 0 && gy < HH && gx >= 0 && gx < WW)
                v = *(const uint4*)(xtb + (size_t)(gy * WW + gx) * CIN + kc * 32 + icq * 8);
            *(uint4*)(s_x + pix * 64 + icq * 16) = v;
        }
        // stage A tile: all 9 taps x 64 oc x 32 ic
        for (int u = tid; u < 2304; u += 256) {
            int icq = u & 3, oc = (u >> 2) & 63, tap = u >> 8;
            *(uint4*)(s_a + u * 16) =
                *(const uint4*)(dynb + (size_t)(tap * COUT + oc0 + oc) * CIN + kc * 32 + icq * 8);
        }
        __syncthreads();
#pragma unroll
        for (int tap = 0; tap < 9; ++tap) {
            short8 af[4];
#pragma unroll
            for (int mf = 0; mf < 4; ++mf)
                af[mf] = *(const short8*)(s_a + (tap * 64 + mf * 16 + lq) * 64 + quad * 16);
            int toff = ((tap / 3) * 58 + (tap % 3)) * 64;
#pragma unroll
            for (int nf = 0; nf < 7; ++nf) {
                short8 bf = *(const short8*)(s_x + pixaddr[nf] + toff);
#pragma unroll
                for (int mf = 0; mf < 4; ++mf)
                    acc[mf][nf] = __builtin_amdgcn_mfma_f32_16x16x32_bf16(af[mf], bf, acc[mf][nf], 0, 0, 0);
            }
        }
    }

    // epilogue: D[m=quad*4+r][n=lq]; out offset = (b,oc)*HW + (r0+wn*2)*56 + n
#pragma unroll
    for (int mf = 0; mf < 4; ++mf) {
#pragma unroll
        for (int r = 0; r < 4; ++r) {
            int oc = oc0 + mf * 16 + quad * 4 + r;
            float bs = bias[oc];
            float* ob = out + (size_t)(b * COUT + oc) * HW + (r0 + wn * 2) * 56 + lq;
#pragma unroll
            for (int nf = 0; nf < 7; ++nf)
                ob[nf * 16] = acc[mf][nf][r] + bs;
        }
    }
}

// ---------------------------------------------------------------------------
extern "C" void kernel_launch(void* const* d_in, const int* in_sizes, int n_in,
                              void* d_out, int out_size, void* d_ws, size_t ws_size,
                              hipStream_t stream) {
    const float* x    = (const float*)d_in[0];
    const float* base = (const float*)d_in[1];
    const float* bias = (const float*)d_in[2];
    const float* wsp  = (const float*)d_in[3];
    const float* bsp  = (const float*)d_in[4];
    const float* win  = (const float*)d_in[5];
    const float* bin  = (const float*)d_in[6];
    const float* wout = (const float*)d_in[7];
    const float* bout = (const float*)d_in[8];
    const float* wk   = (const float*)d_in[9];
    const float* bk   = (const float*)d_in[10];
    float* out = (float*)d_out;
    char* ws = (char*)d_ws;

    float* ctx  = (float*)(ws + WSB_CTX);
    float* asp  = (float*)(ws + WSB_ASP);
    float* ain  = (float*)(ws + WSB_AIN);
    float* aout = (float*)(ws + WSB_AOUT);
    unsigned short* xt  = (unsigned short*)(ws + WSB_XT);
    unsigned short* dyn = (unsigned short*)(ws + WSB_DYN);

    k_context<<<BATCH * CIN, 256, 0, stream>>>(x, ctx);
    k_xt<<<dim3(HW / 64, BATCH), 256, 0, stream>>>(x, xt);
    k_attn<<<(BATCH * 393) / 4, 256, 0, stream>>>(ctx, wsp, bsp, win, bin, wout, bout, asp, ain, aout);
    k_build<<<NE / 256, 256, 0, stream>>>(ctx, wk, bk, base, asp, ain, aout, dyn);
    k_conv<<<dim3(HH / 8, COUT / 64, BATCH), 256, 0, stream>>>(xt, dyn, bias, out);
}

// Round 4
// 322.375 us; speedup vs baseline: 2.2558x; 1.0314x over previous
//
#include <hip/hip_runtime.h>
#include <hip/hip_bf16.h>
#include <math.h>

#define BATCH 16
#define CIN   128
#define COUT  256
#define HH    56
#define WW    56
#define HW    3136
#define NTAP  9
#define NE    (COUT*CIN*NTAP)   // 294912

typedef short short8 __attribute__((ext_vector_type(8)));
typedef float floatx4 __attribute__((ext_vector_type(4)));

// workspace layout (byte offsets, all 256-aligned)
#define WSB_CTX   0                          // fp32 [16][128]
#define WSB_ASP   8192                       // fp32 [16][16] (9 used)
#define WSB_AIN   9472                       // fp32 [16][128]
#define WSB_AOUT  17664                      // fp32 [16][256]
#define WSB_XT    34048                      // bf16 [16][3136][128]
#define WSB_DYN   (WSB_XT + BATCH*HW*CIN*2)  // bf16 [16][9][256][128]  (tap,oc,ic)

// fp32 -> bf16 RNE
static __device__ inline unsigned short f2b(float f) {
    union { float f; unsigned u; } v; v.f = f;
    unsigned r = v.u + 0x7FFF + ((v.u >> 16) & 1);
    return (unsigned short)(r >> 16);
}
static __device__ inline short8 pack8(float4 a, float4 b) {
    short8 r;
    r[0] = (short)f2b(a.x); r[1] = (short)f2b(a.y); r[2] = (short)f2b(a.z); r[3] = (short)f2b(a.w);
    r[4] = (short)f2b(b.x); r[5] = (short)f2b(b.y); r[6] = (short)f2b(b.z); r[7] = (short)f2b(b.w);
    return r;
}

// ---------------------------------------------------------------------------
// K1: context[b,c] = mean(x[b,c,:,:])
__global__ void k_context(const float* __restrict__ x, float* __restrict__ ctx) {
    int bc = blockIdx.x;
    const float4* p = (const float4*)(x + (size_t)bc * HW);
    float s = 0.f;
    for (int i = threadIdx.x; i < HW / 4; i += 256) { float4 v = p[i]; s += v.x + v.y + v.z + v.w; }
    for (int off = 32; off; off >>= 1) s += __shfl_down(s, off, 64);
    __shared__ float red[4];
    if ((threadIdx.x & 63) == 0) red[threadIdx.x >> 6] = s;
    __syncthreads();
    if (threadIdx.x == 0) ctx[bc] = (red[0] + red[1] + red[2] + red[3]) * (1.f / (float)HW);
}

// ---------------------------------------------------------------------------
// K2: small gates — one wave per GEMV row
__global__ void k_attn(const float* __restrict__ ctx,
                       const float* __restrict__ wsp, const float* __restrict__ bsp,
                       const float* __restrict__ win, const float* __restrict__ bin,
                       const float* __restrict__ wout, const float* __restrict__ bout,
                       float* __restrict__ asp, float* __restrict__ ain, float* __restrict__ aout) {
    int R = blockIdx.x * 4 + (threadIdx.x >> 6);
    int lane = threadIdx.x & 63;
    int b = R / 393, r = R % 393;
    const float* w; float bias; float* o;
    if (r < 9)        { w = wsp  + r * CIN;         bias = bsp[r];         o = asp  + b * 16  + r; }
    else if (r < 137) { w = win  + (r - 9) * CIN;   bias = bin[r - 9];     o = ain  + b * CIN + (r - 9); }
    else              { w = wout + (r - 137) * CIN; bias = bout[r - 137];  o = aout + b * COUT + (r - 137); }
    float2 wv = ((const float2*)w)[lane];
    float2 cv = ((const float2*)(ctx + b * CIN))[lane];
    float d = wv.x * cv.x + wv.y * cv.y;
    for (int off = 32; off; off >>= 1) d += __shfl_down(d, off, 64);
    if (lane == 0) *o = 1.f / (1.f + __expf(-(d + bias)));
}

// ---------------------------------------------------------------------------
// K3 fat kernel: blocks [0,784) do the x transpose+cast (xt), blocks
// [784, 784+1152) do the dyn build (independent work, overlapped in one launch).
#define XT_BLOCKS    784          // 49 * 16
#define BUILD_BLOCKS 1152         // NE / 256
__global__ void k_fat(const float* __restrict__ x, unsigned short* __restrict__ xt,
                      const float* __restrict__ ctx, const float* __restrict__ wk,
                      const float* __restrict__ bk, const float* __restrict__ base,
                      const float* __restrict__ asp, const float* __restrict__ ain,
                      const float* __restrict__ aout, unsigned short* __restrict__ dyn) {
    if (blockIdx.x < XT_BLOCKS) {
        // ---- xt: [b][pix][ic] bf16; thread: 1 pixel x 32 ic ----
        int bid = blockIdx.x;
        int b = bid / 49;
        int p = (bid % 49) * 64 + (threadIdx.x & 63);
        int icq = threadIdx.x >> 6;
        const float* xb = x + (size_t)b * CIN * HW + p;
        unsigned short tmp[32];
#pragma unroll
        for (int j = 0; j < 32; ++j) tmp[j] = f2b(xb[(size_t)(icq * 32 + j) * HW]);
        uint4* dst = (uint4*)(xt + ((size_t)b * HW + p) * CIN + icq * 32);
        const uint4* s = (const uint4*)tmp;
        dst[0] = s[0]; dst[1] = s[1]; dst[2] = s[2]; dst[3] = s[3];
        return;
    }
    // ---- build: skinny MFMA GEMM, 64 n per wave (4 frags of 16) ----
    int bid = blockIdx.x - XT_BLOCKS;
    int wid = threadIdx.x >> 6, l = threadIdx.x & 63;
    int lq = l & 15, quad = l >> 4;
    short8 afr[4];
    const float* arow = ctx + lq * CIN;
#pragma unroll
    for (int kc = 0; kc < 4; ++kc) {
        float4 v0 = *(const float4*)(arow + kc * 32 + quad * 8);
        float4 v1 = *(const float4*)(arow + kc * 32 + quad * 8 + 4);
        afr[kc] = pack8(v0, v1);
    }
    int n0w = bid * 256 + wid * 64;
    for (int nf = 0; nf < 4; ++nf) {
        int n0 = n0w + nf * 16;
        int ic  = (n0 & 127) + lq;
        int oc  = (n0 >> 7) & 255;
        int tap = n0 >> 15;
        int e = (oc * CIN + ic) * NTAP + tap;
        const float* wrow = wk + (size_t)e * CIN;
        floatx4 acc = {0.f, 0.f, 0.f, 0.f};
#pragma unroll
        for (int kc = 0; kc < 4; ++kc) {
            float4 v0 = *(const float4*)(wrow + kc * 32 + quad * 8);
            float4 v1 = *(const float4*)(wrow + kc * 32 + quad * 8 + 4);
            short8 bfr = pack8(v0, v1);
            acc = __builtin_amdgcn_mfma_f32_16x16x32_bf16(afr[kc], bfr, acc, 0, 0, 0);
        }
        float bke = bk[e], bse = base[e];
#pragma unroll
        for (int r = 0; r < 4; ++r) {
            int b = quad * 4 + r;
            float s = 1.f / (1.f + __expf(-(acc[r] + bke)));
            float v = bse * s * aout[b * COUT + oc] * ain[b * CIN + ic] * asp[b * 16 + tap];
            dyn[(size_t)b * NE + n0 + lq] = f2b(v);
        }
    }
}

// ---------------------------------------------------------------------------
// K4: conv as MFMA implicit GEMM. 1-D grid of 448 blocks, XCD-swizzled:
// id%8 is invariant across the 7 row-blocks of a (b,oc)-pair AND across the
// 4 oc-pairs of a batch -> per-XCD working set (x[b] x2 + dyn slices) fits L2.
// Block: 64 oc x 8 output rows; A-tile (9 taps x 64 oc x 32 ic) + x-tile
// (10 x 58 x 32 ic) in LDS; 2 barriers per ic-chunk; 4 waves, each
// 4 m-frags x 7 n-frags (16x16x32 bf16).
__global__ __launch_bounds__(256, 2) void k_conv(
    const unsigned short* __restrict__ xt, const unsigned short* __restrict__ dyn,
    const float* __restrict__ bias, float* __restrict__ out) {
    __shared__ char s_x[580 * 64];   // [tr*58+col][32 ic], 64-B rows
    __shared__ char s_a[576 * 64];   // [tap*64+oc][32 ic]
    // decode swizzled id: p = oc*16 + b (pair), r = row-block
    int id  = blockIdx.x;
    int low = id & 7;
    int q   = id >> 3;
    int r   = q % 7;
    int phi = q / 7;
    int p   = phi * 8 + low;
    int oc0 = (p >> 4) * 64;
    int b   = p & 15;
    int r0  = r * 8;

    int tid = threadIdx.x;
    int wn = tid >> 6, l = tid & 63, lq = l & 15, quad = l >> 4;
    const unsigned short* xtb  = xt  + (size_t)b * HW * CIN;
    const unsigned short* dynb = dyn + (size_t)b * NE;

    int pixaddr[7];
#pragma unroll
    for (int nf = 0; nf < 7; ++nf) {
        int n = nf * 16 + lq;                       // 0..111 within wave's 2 rows
        int tr = wn * 2 + n / 56, col = n % 56;
        pixaddr[nf] = (tr * 58 + col) * 64 + quad * 16;
    }

    floatx4 acc[4][7];
#pragma unroll
    for (int i = 0; i < 4; ++i)
#pragma unroll
        for (int j = 0; j < 7; ++j) acc[i][j] = (floatx4){0.f, 0.f, 0.f, 0.f};

    int cx  = tid & 63;
    int icq = tid >> 6;
    for (int kc = 0; kc < 4; ++kc) {
        __syncthreads();
        // stage x tile: rows r0-1..r0+8, cols -1..56, zero-padded (div-free)
#pragma unroll
        for (int ry = 0; ry < 10; ++ry) {
            if (cx < 58) {
                int gy = r0 + ry - 1, gx = cx - 1;
                uint4 v = {0u, 0u, 0u, 0u};
                if (gy >= 0 && gy < HH && gx >= 0 && gx < WW)
                    v = *(const uint4*)(xtb + (size_t)(gy * WW + gx) * CIN + kc * 32 + icq * 8);
                *(uint4*)(s_x + (ry * 58 + cx) * 64 + icq * 16) = v;
            }
        }
        // stage A tile: all 9 taps x 64 oc x 32 ic
        for (int u = tid; u < 2304; u += 256) {
            int icq2 = u & 3, oc = (u >> 2) & 63, tap = u >> 8;
            *(uint4*)(s_a + u * 16) =
                *(const uint4*)(dynb + (size_t)(tap * COUT + oc0 + oc) * CIN + kc * 32 + icq2 * 8);
        }
        __syncthreads();
#pragma unroll
        for (int tap = 0; tap < 9; ++tap) {
            short8 af[4];
#pragma unroll
            for (int mf = 0; mf < 4; ++mf)
                af[mf] = *(const short8*)(s_a + (tap * 64 + mf * 16 + lq) * 64 + quad * 16);
            int toff = ((tap / 3) * 58 + (tap % 3)) * 64;
#pragma unroll
            for (int nf = 0; nf < 7; ++nf) {
                short8 bf = *(const short8*)(s_x + pixaddr[nf] + toff);
#pragma unroll
                for (int mf = 0; mf < 4; ++mf)
                    acc[mf][nf] = __builtin_amdgcn_mfma_f32_16x16x32_bf16(af[mf], bf, acc[mf][nf], 0, 0, 0);
            }
        }
    }

    // epilogue: D[m=quad*4+r][n=lq]
#pragma unroll
    for (int mf = 0; mf < 4; ++mf) {
#pragma unroll
        for (int rr = 0; rr < 4; ++rr) {
            int oc = oc0 + mf * 16 + quad * 4 + rr;
            float bs = bias[oc];
            float* ob = out + (size_t)(b * COUT + oc) * HW + (r0 + wn * 2) * 56 + lq;
#pragma unroll
            for (int nf = 0; nf < 7; ++nf)
                ob[nf * 16] = acc[mf][nf][rr] + bs;
        }
    }
}

// ---------------------------------------------------------------------------
extern "C" void kernel_launch(void* const* d_in, const int* in_sizes, int n_in,
                              void* d_out, int out_size, void* d_ws, size_t ws_size,
                              hipStream_t stream) {
    const float* x    = (const float*)d_in[0];
    const float* base = (const float*)d_in[1];
    const float* bias = (const float*)d_in[2];
    const float* wsp  = (const float*)d_in[3];
    const float* bsp  = (const float*)d_in[4];
    const float* win  = (const float*)d_in[5];
    const float* bin  = (const float*)d_in[6];
    const float* wout = (const float*)d_in[7];
    const float* bout = (const float*)d_in[8];
    const float* wk   = (const float*)d_in[9];
    const float* bk   = (const float*)d_in[10];
    float* out = (float*)d_out;
    char* ws = (char*)d_ws;

    float* ctx  = (float*)(ws + WSB_CTX);
    float* asp  = (float*)(ws + WSB_ASP);
    float* ain  = (float*)(ws + WSB_AIN);
    float* aout = (float*)(ws + WSB_AOUT);
    unsigned short* xt  = (unsigned short*)(ws + WSB_XT);
    unsigned short* dyn = (unsigned short*)(ws + WSB_DYN);

    k_context<<<BATCH * CIN, 256, 0, stream>>>(x, ctx);
    k_attn<<<(BATCH * 393) / 4, 256, 0, stream>>>(ctx, wsp, bsp, win, bin, wout, bout, asp, ain, aout);
    k_fat<<<XT_BLOCKS + BUILD_BLOCKS, 256, 0, stream>>>(x, xt, ctx, wk, bk, base, asp, ain, aout, dyn);
    k_conv<<<448, 256, 0, stream>>>(xt, dyn, bias, out);
}